// Round 7
// baseline (34.411 us; speedup 1.0000x reference)
//
#include <hip/hip_runtime.h>

// N = 16,777,216 fp32 probabilities + int32 {0,1} targets.
//   count      = #{ p > 0.5 && t == 0 }
//   out        = mean( -(t*log p + (1-t)*log(1-p)) ) * (1 + 0.1*count)
//
// R1-R3: 79/65/62 us — plateau was f64 atomicAdd (CAS retry loop).
// R4:    disjoint partials + tiny 2nd kernel, no atomics: 30.9 us.
// R5:    fused ticket + __threadfence: 96 us — per-block device fence emits
//        whole-L2 writeback x2048. Never fence per-block on gfx950. Reverted.
// R6:    + nontemporal loads (L2-bypass for no-reuse streams): 28.0 us.
//        Harness fill kernels show ~7.0 TB/s write ceiling; read phase is
//        ~22 us (~6.1 TB/s effective) -> near read floor. Residual = final
//        kernel + 2 graph nodes.
// R7:    pack each block's partial into ONE float2 (fp32 sum, count bits):
//        halves cl_final's loads, single dwordx2 store per block.

#define N_ELEM  16777216
#define N_VEC4  (N_ELEM / 4)       // 4,194,304
#define BLOCKS  2048
#define TPB     256
#define NTHREAD (BLOCKS * TPB)     // 524,288
#define NITER   (N_VEC4 / NTHREAD) // exactly 8

typedef float f4v __attribute__((ext_vector_type(4)));
typedef int   i4v __attribute__((ext_vector_type(4)));

// d_ws layout: [0 .. 16384) float2 part[2048]  {.x = loss sum, .y = count bits}

__global__ __launch_bounds__(TPB, 4) void cl_reduce(
    const f4v* __restrict__ p4,
    const i4v* __restrict__ t4,
    float2*    __restrict__ part)
{
    const int tid = blockIdx.x * TPB + threadIdx.x;

    f4v p[NITER];
    i4v t[NITER];
    #pragma unroll
    for (int j = 0; j < NITER; ++j) {
        p[j] = __builtin_nontemporal_load(&p4[tid + j * NTHREAD]);
        t[j] = __builtin_nontemporal_load(&t4[tid + j * NTHREAD]);
    }
    __builtin_amdgcn_sched_barrier(0);

    float        lsum = 0.0f;
    unsigned int lcnt = 0u;
    #pragma unroll
    for (int j = 0; j < NITER; ++j) {
        lsum += __logf(t[j][0] ? p[j][0] : 1.0f - p[j][0]);
        lsum += __logf(t[j][1] ? p[j][1] : 1.0f - p[j][1]);
        lsum += __logf(t[j][2] ? p[j][2] : 1.0f - p[j][2]);
        lsum += __logf(t[j][3] ? p[j][3] : 1.0f - p[j][3]);
        lcnt += (unsigned int)((p[j][0] > 0.5f) & (t[j][0] == 0));
        lcnt += (unsigned int)((p[j][1] > 0.5f) & (t[j][1] == 0));
        lcnt += (unsigned int)((p[j][2] > 0.5f) & (t[j][2] == 0));
        lcnt += (unsigned int)((p[j][3] > 0.5f) & (t[j][3] == 0));
    }
    lsum = -lsum;

    // 64-lane wave reduction
    #pragma unroll
    for (int off = 32; off > 0; off >>= 1) {
        lsum += __shfl_down(lsum, off);
        lcnt += __shfl_down(lcnt, off);
    }

    // block reduction across 4 waves -> ONE dwordx2 store per block, no atomics
    __shared__ float        s_sum[4];
    __shared__ unsigned int s_cnt[4];
    const int wave = threadIdx.x >> 6;
    const int lane = threadIdx.x & 63;
    if (lane == 0) { s_sum[wave] = lsum; s_cnt[wave] = lcnt; }
    __syncthreads();
    if (threadIdx.x == 0) {
        float2 v;
        v.x = s_sum[0] + s_sum[1] + s_sum[2] + s_sum[3];
        v.y = __uint_as_float(s_cnt[0] + s_cnt[1] + s_cnt[2] + s_cnt[3]);
        part[blockIdx.x] = v;
    }
}

__global__ __launch_bounds__(TPB) void cl_final(
    const float2* __restrict__ part,
    float*        __restrict__ out)
{
    double       s = 0.0;
    unsigned int c = 0u;
    #pragma unroll
    for (int j = 0; j < BLOCKS / TPB; ++j) {   // 8 float2 per thread
        const float2 v = part[threadIdx.x + j * TPB];
        s += (double)v.x;
        c += __float_as_uint(v.y);
    }
    #pragma unroll
    for (int off = 32; off > 0; off >>= 1) {
        s += __shfl_down(s, off);
        c += __shfl_down(c, off);
    }
    __shared__ double       ss[4];
    __shared__ unsigned int sc[4];
    const int wave = threadIdx.x >> 6;
    const int lane = threadIdx.x & 63;
    if (lane == 0) { ss[wave] = s; sc[wave] = c; }
    __syncthreads();
    if (threadIdx.x == 0) {
        const double       tot = ss[0] + ss[1] + ss[2] + ss[3];
        const unsigned int tc  = sc[0] + sc[1] + sc[2] + sc[3];
        out[0] = (float)((tot * (1.0 / (double)N_ELEM)) * (1.0 + 0.1 * (double)tc));
    }
}

extern "C" void kernel_launch(void* const* d_in, const int* in_sizes, int n_in,
                              void* d_out, int out_size, void* d_ws, size_t ws_size,
                              hipStream_t stream) {
    const f4v* p4  = (const f4v*)d_in[0];
    const i4v* t4  = (const i4v*)d_in[1];
    float*     out = (float*)d_out;
    float2*    part = (float2*)d_ws;

    cl_reduce<<<BLOCKS, TPB, 0, stream>>>(p4, t4, part);
    cl_final<<<1, TPB, 0, stream>>>(part, out);
}